// Round 4
// baseline (82.106 us; speedup 1.0000x reference)
//
#include <hip/hip_runtime.h>

// x[2][4][128][128][128] f32, y[2][1][128][128][128] int32
constexpr float EPSV = 1e-6f;
constexpr int ZSEG = 8;                  // z-slices per wave
constexpr int NSEG = 128 / ZSEG;         // 16 segments
constexpr int NWAVE = 2 * 4 * NSEG * 128;  // b * class * zseg * y = 16384 waves
constexpr int NBLK = NWAVE / 4;          // 4096 blocks of 4 waves

// Per-slice ring state for ONE class plane:
//  ypx/ypy: y-direction product of (1-x) at x0 / x0+1
//  cxx/cxy: raw center-row x values
//  bits: bit0 = presence of cls in 3 y-rows at x0, bit8 = same at x0+1,
//        bit1 = (center class == cls) at x0, bit9 = same at x0+1
struct Ring {
    float ypx, ypy, cxx, cxy;
    int bits;
};

__device__ __forceinline__ Ring load_ring(const float* __restrict__ xp,
                                          const int* __restrict__ yb,
                                          int s, int rbase0, bool ym1, bool yp1,
                                          int cls) {
    Ring r;
    const int rb = (s << 14) | rbase0;

    int2 vm = ym1 ? *(const int2*)(yb + rb - 128) : make_int2(-1, -1);
    int2 vc = *(const int2*)(yb + rb);
    int2 vp = yp1 ? *(const int2*)(yb + rb + 128) : make_int2(-1, -1);
    const int por0 = (vm.x == cls) | (vc.x == cls) | (vp.x == cls);
    const int por1 = (vm.y == cls) | (vc.y == cls) | (vp.y == cls);
    r.bits = por0 | (por1 << 8) | ((vc.x == cls) << 1) | ((vc.y == cls) << 9);

    float2 am = ym1 ? *(const float2*)(xp + rb - 128) : make_float2(0.f, 0.f);
    float2 ac = *(const float2*)(xp + rb);
    float2 ap = yp1 ? *(const float2*)(xp + rb + 128) : make_float2(0.f, 0.f);
    r.cxx = ac.x;
    r.cxy = ac.y;
    r.ypx = (1.f - am.x) * (1.f - ac.x) * (1.f - ap.x);
    r.ypy = (1.f - am.y) * (1.f - ac.y) * (1.f - ap.y);
    return r;
}

__device__ __forceinline__ Ring ones_ring() {
    Ring r;
    r.ypx = 1.f; r.ypy = 1.f; r.cxx = 0.f; r.cxy = 0.f; r.bits = 0;
    return r;
}

__global__ __launch_bounds__(256) void lah_stencil(const float* __restrict__ x,
                                                   const int* __restrict__ y32,
                                                   float* __restrict__ acc) {
    const int wid = (blockIdx.x << 2) | (threadIdx.x >> 6);
    const int lane = threadIdx.x & 63;
    const int yy = wid & 127;
    const int zs = (wid >> 7) & (NSEG - 1);
    const int cls = (wid >> 11) & 3;
    const int b = (wid >> 13) & 1;
    const int x0 = lane << 1;
    const int z0 = zs * ZSEG;
    const bool ym1 = yy > 0, yp1v = yy < 127;
    const int rbase0 = (yy << 7) | x0;

    const float* __restrict__ xp = x + ((long)(b * 4 + cls) << 21);
    const int* __restrict__ yb = y32 + ((long)b << 21);

    float fp = 0.f, fnv = 0.f, sx = 0.f, sy = 0.f;

    Ring r0 = (z0 > 0) ? load_ring(xp, yb, z0 - 1, rbase0, ym1, yp1v, cls) : ones_ring();
    Ring r1 = load_ring(xp, yb, z0, rbase0, ym1, yp1v, cls);

#pragma unroll
    for (int dz = 0; dz < ZSEG; ++dz) {
        const int z = z0 + dz;
        Ring r2 = (z + 1 < 128) ? load_ring(xp, yb, z + 1, rbase0, ym1, yp1v, cls)
                                : ones_ring();

        // presence across z (por bits), then across x via shuffles
        const int zor = (r0.bits | r1.bits | r2.bits) & 0x0101;
        int orL = __shfl_up(zor, 1);
        if (lane == 0) orL = 0;
        int orR = __shfl_down(zor, 1);
        if (lane == 63) orR = 0;
        const int pres0 = (zor | (zor >> 8) | (orL >> 8)) & 1;
        const int pres1 = ((zor >> 8) | zor | orR) & 1;
        const int eq0 = (r1.bits >> 1) & 1;
        const int eq1 = (r1.bits >> 9) & 1;

        // 3x3x3 product of (1-x): z-product then x via shuffles
        const float zpx = r0.ypx * r1.ypx * r2.ypx;
        const float zpy = r0.ypy * r1.ypy * r2.ypy;
        float zpL = __shfl_up(zpy, 1);
        if (lane == 0) zpL = 1.f;
        float zpR = __shfl_down(zpx, 1);
        if (lane == 63) zpR = 1.f;
        const float P0 = zpL * zpx * zpy;
        const float P1 = zpx * zpy * zpR;

        const float xv0 = r1.cxx, xv1 = r1.cxy;
        sx += xv0 + xv1;
        fp += eq0 ? 0.f : xv0 * (pres0 ? 1.f : 2.f);
        fp += eq1 ? 0.f : xv1 * (pres1 ? 1.f : 2.f);
        fnv += eq0 ? (1.f - xv0) * (1.f + P0) : 0.f;
        fnv += eq1 ? (1.f - xv1) * (1.f + P1) : 0.f;
        sy += (float)(eq0 + eq1);

        r0 = r1;
        r1 = r2;
    }

    // ---- reduce 4 scalars: wave shuffle -> block LDS -> global atomics ----
    float r[4] = {fp, fnv, sx, sy};
    __shared__ float s[4];
#pragma unroll
    for (int i = 0; i < 4; ++i) {
        float vv = r[i];
#pragma unroll
        for (int off = 32; off >= 1; off >>= 1) vv += __shfl_down(vv, off);
        r[i] = vv;
    }
    if (threadIdx.x < 4) s[threadIdx.x] = 0.f;
    __syncthreads();
    if (lane == 0) {
#pragma unroll
        for (int i = 0; i < 4; ++i) atomicAdd(&s[i], r[i]);
    }
    __syncthreads();
    // all 4 waves in a block share (b, cls); slot = b*16 + q*4 + cls
    if (threadIdx.x < 4)
        atomicAdd(&acc[b * 16 + threadIdx.x * 4 + cls], s[threadIdx.x]);
}

__global__ void lah_finalize(const float* __restrict__ acc, float* __restrict__ out) {
    float loss = 0.f;
#pragma unroll
    for (int b = 0; b < 2; ++b) {
#pragma unroll
        for (int c = 1; c < 4; ++c) {
            const float fp = acc[b * 16 + 0 + c];
            const float fn = acc[b * 16 + 4 + c];
            const float sxv = acc[b * 16 + 8 + c];
            const float syv = acc[b * 16 + 12 + c];
            loss += fmaxf(fp / (sxv + EPSV), fn / (syv + EPSV));
        }
    }
    out[0] = loss / 6.f;
}

extern "C" void kernel_launch(void* const* d_in, const int* in_sizes, int n_in,
                              void* d_out, int out_size, void* d_ws, size_t ws_size,
                              hipStream_t stream) {
    const float* x = (const float*)d_in[0];
    const int* y32 = (const int*)d_in[1];
    float* out = (float*)d_out;
    float* acc = (float*)d_ws;  // 32 floats

    hipMemsetAsync(d_ws, 0, 32 * sizeof(float), stream);
    lah_stencil<<<NBLK, 256, 0, stream>>>(x, y32, acc);
    lah_finalize<<<1, 1, 0, stream>>>(acc, out);
}

// Round 5
// 71.801 us; speedup vs baseline: 1.1435x; 1.1435x over previous
//
#include <hip/hip_runtime.h>

// x[2][4][128][128][128] f32, y[2][1][128][128][128] int32
constexpr int SPB = 1 << 21;
constexpr float EPSV = 1e-6f;

// Static scratch: packed per-voxel mask, 4 MB.
// mask[v] = (center_class << 4) | OR_{dz,dy,dx in 3x3x3, clipped}(1 << y[v+d])
__device__ unsigned char g_mask[2 * SPB];

// ===========================================================================
// K0: build packed 27-neighborhood presence mask + center class
// ===========================================================================
constexpr int K0_ZSEG = 4;
constexpr int K0_NWAVE = 2 * (128 / K0_ZSEG) * 128;  // 8192
constexpr int K0_NBLK = K0_NWAVE / 4;

struct MEnt { int pk, cx, cy; };  // pk: nib(x0) | nib(x0+1)<<8, y-OR'd

__device__ __forceinline__ MEnt k0_load(const int* __restrict__ yb, int s,
                                        int rbase0, bool ym1, bool yp1) {
    MEnt e;
    const int rb = (s << 14) | rbase0;
    int2 vc = *(const int2*)(yb + rb);
    int nib0 = 1 << vc.x, nib1 = 1 << vc.y;
    if (ym1) { int2 vm = *(const int2*)(yb + rb - 128); nib0 |= 1 << vm.x; nib1 |= 1 << vm.y; }
    if (yp1) { int2 vp = *(const int2*)(yb + rb + 128); nib0 |= 1 << vp.x; nib1 |= 1 << vp.y; }
    e.pk = nib0 | (nib1 << 8);
    e.cx = vc.x; e.cy = vc.y;
    return e;
}

__global__ __launch_bounds__(256) void mask_build(const int* __restrict__ y32) {
    const int wid = (blockIdx.x << 2) | (threadIdx.x >> 6);
    const int lane = threadIdx.x & 63;
    const int yy = wid & 127;
    const int zs = (wid >> 7) & 31;
    const int b = (wid >> 12) & 1;
    const int x0 = lane << 1;
    const int z0 = zs * K0_ZSEG;
    const bool ym1 = yy > 0, yp1 = yy < 127;
    const int rbase0 = (yy << 7) | x0;

    const int* __restrict__ yb = y32 + ((long)b << 21);
    unsigned char* __restrict__ mb = g_mask + ((long)b << 21);

    MEnt e0, e1;
    if (z0 > 0) e0 = k0_load(yb, z0 - 1, rbase0, ym1, yp1);
    else { e0.pk = 0; e0.cx = 0; e0.cy = 0; }
    e1 = k0_load(yb, z0, rbase0, ym1, yp1);

#pragma unroll
    for (int dz = 0; dz < K0_ZSEG; ++dz) {
        const int z = z0 + dz;
        MEnt e2;
        if (z + 1 < 128) e2 = k0_load(yb, z + 1, rbase0, ym1, yp1);
        else { e2.pk = 0; e2.cx = 0; e2.cy = 0; }

        const int zor = e0.pk | e1.pk | e2.pk;
        int orL = __shfl_up(zor, 1);
        if (lane == 0) orL = 0;
        int orR = __shfl_down(zor, 1);
        if (lane == 63) orR = 0;
        const int full0 = (zor | (zor >> 8) | (orL >> 8)) & 15;
        const int full1 = (zor | (zor >> 8) | orR) & 15;

        const unsigned short st =
            (unsigned short)((full0 | (e1.cx << 4)) | ((full1 | (e1.cy << 4)) << 8));
        *(unsigned short*)(mb + ((z << 14) | rbase0)) = st;

        e0 = e1; e1 = e2;
    }
}

// ===========================================================================
// K1: main fused pass — per (b, class, z-seg, y-pair), 2 y-streams per wave
// ===========================================================================
constexpr int ZSEG = 8;
constexpr int NSEG = 128 / ZSEG;             // 16
constexpr int NWAVE = 2 * 4 * NSEG * 64;     // 8192
constexpr int NBLK = NWAVE / 4;              // 2048

struct XEnt { float ypx, ypy, cxx, cxy; };

__device__ __forceinline__ XEnt xload(const float* __restrict__ xp, int s,
                                      int rb, bool ym1, bool yp1) {
    const int a = (s << 14) | rb;
    float2 ac = *(const float2*)(xp + a);
    float px = 1.f - ac.x, py = 1.f - ac.y;
    if (ym1) { float2 am = *(const float2*)(xp + a - 128); px *= (1.f - am.x); py *= (1.f - am.y); }
    if (yp1) { float2 ap = *(const float2*)(xp + a + 128); px *= (1.f - ap.x); py *= (1.f - ap.y); }
    XEnt e; e.ypx = px; e.ypy = py; e.cxx = ac.x; e.cxy = ac.y;
    return e;
}

__device__ __forceinline__ XEnt ones_ent() {
    XEnt e; e.ypx = 1.f; e.ypy = 1.f; e.cxx = 0.f; e.cxy = 0.f;
    return e;
}

__global__ __launch_bounds__(256) void lah_main(const float* __restrict__ x,
                                                float* __restrict__ acc) {
    const int wid = (blockIdx.x << 2) | (threadIdx.x >> 6);
    const int lane = threadIdx.x & 63;
    const int yp = wid & 63;            // y-pair index
    const int zs = (wid >> 6) & (NSEG - 1);
    const int cls = (wid >> 10) & 3;
    const int b = (wid >> 12) & 1;
    const int x0 = lane << 1;
    const int z0 = zs * ZSEG;

    const int yyA = yp;                 // 0..63  (yp1 always true)
    const int yyB = yp + 64;            // 64..127 (ym1 always true)
    const bool ym1A = yyA > 0;
    const bool yp1B = yyB < 127;
    const int rbA = (yyA << 7) | x0;
    const int rbB = (yyB << 7) | x0;

    const float* __restrict__ xp = x + ((long)(b * 4 + cls) << 21);
    const unsigned char* __restrict__ mb = g_mask + ((long)b << 21);

    float fp = 0.f, fn = 0.f, sx = 0.f, sy = 0.f;

    XEnt a0 = (z0 > 0) ? xload(xp, z0 - 1, rbA, ym1A, true) : ones_ent();
    XEnt b0 = (z0 > 0) ? xload(xp, z0 - 1, rbB, true, yp1B) : ones_ent();
    XEnt a1 = xload(xp, z0, rbA, ym1A, true);
    XEnt b1 = xload(xp, z0, rbB, true, yp1B);
    int mkA = *(const unsigned short*)(mb + ((z0 << 14) | rbA));
    int mkB = *(const unsigned short*)(mb + ((z0 << 14) | rbB));

#pragma unroll
    for (int dz = 0; dz < ZSEG; ++dz) {
        const int z = z0 + dz;
        // --- issue all loads for next slice first (both streams) ---
        XEnt a2 = (z + 1 < 128) ? xload(xp, z + 1, rbA, ym1A, true) : ones_ent();
        XEnt b2 = (z + 1 < 128) ? xload(xp, z + 1, rbB, true, yp1B) : ones_ent();
        int nmA = 0, nmB = 0;
        if (dz < ZSEG - 1) {
            nmA = *(const unsigned short*)(mb + (((z + 1) << 14) | rbA));
            nmB = *(const unsigned short*)(mb + (((z + 1) << 14) | rbB));
        }

        // --- stream A compute ---
        {
            const float zpx = a0.ypx * a1.ypx * a2.ypx;
            const float zpy = a0.ypy * a1.ypy * a2.ypy;
            float zpL = __shfl_up(zpy, 1);
            if (lane == 0) zpL = 1.f;
            float zpR = __shfl_down(zpx, 1);
            if (lane == 63) zpR = 1.f;
            const float t = zpx * zpy;
            const float P0 = zpL * t, P1 = t * zpR;
            const int m0 = mkA & 0xFF, m1 = mkA >> 8;
            const bool pr0 = (m0 >> cls) & 1, pr1 = (m1 >> cls) & 1;
            const bool eq0 = (m0 >> 4) == cls, eq1 = (m1 >> 4) == cls;
            const float xv0 = a1.cxx, xv1 = a1.cxy;
            sx += xv0 + xv1;
            fp += eq0 ? 0.f : xv0 * (pr0 ? 1.f : 2.f);
            fp += eq1 ? 0.f : xv1 * (pr1 ? 1.f : 2.f);
            fn += eq0 ? (1.f - xv0) * (1.f + P0) : 0.f;
            fn += eq1 ? (1.f - xv1) * (1.f + P1) : 0.f;
            sy += (eq0 ? 1.f : 0.f) + (eq1 ? 1.f : 0.f);
        }
        // --- stream B compute ---
        {
            const float zpx = b0.ypx * b1.ypx * b2.ypx;
            const float zpy = b0.ypy * b1.ypy * b2.ypy;
            float zpL = __shfl_up(zpy, 1);
            if (lane == 0) zpL = 1.f;
            float zpR = __shfl_down(zpx, 1);
            if (lane == 63) zpR = 1.f;
            const float t = zpx * zpy;
            const float P0 = zpL * t, P1 = t * zpR;
            const int m0 = mkB & 0xFF, m1 = mkB >> 8;
            const bool pr0 = (m0 >> cls) & 1, pr1 = (m1 >> cls) & 1;
            const bool eq0 = (m0 >> 4) == cls, eq1 = (m1 >> 4) == cls;
            const float xv0 = b1.cxx, xv1 = b1.cxy;
            sx += xv0 + xv1;
            fp += eq0 ? 0.f : xv0 * (pr0 ? 1.f : 2.f);
            fp += eq1 ? 0.f : xv1 * (pr1 ? 1.f : 2.f);
            fn += eq0 ? (1.f - xv0) * (1.f + P0) : 0.f;
            fn += eq1 ? (1.f - xv1) * (1.f + P1) : 0.f;
            sy += (eq0 ? 1.f : 0.f) + (eq1 ? 1.f : 0.f);
        }

        a0 = a1; a1 = a2;
        b0 = b1; b1 = b2;
        mkA = nmA; mkB = nmB;
    }

    // ---- reduce 4 scalars: wave shuffle -> block LDS -> global atomics ----
    float r[4] = {fp, fn, sx, sy};
    __shared__ float s[4];
#pragma unroll
    for (int i = 0; i < 4; ++i) {
        float vv = r[i];
#pragma unroll
        for (int off = 32; off >= 1; off >>= 1) vv += __shfl_down(vv, off);
        r[i] = vv;
    }
    if (threadIdx.x < 4) s[threadIdx.x] = 0.f;
    __syncthreads();
    if (lane == 0) {
#pragma unroll
        for (int i = 0; i < 4; ++i) atomicAdd(&s[i], r[i]);
    }
    __syncthreads();
    // all 4 waves in a block share (b, cls); slot = b*16 + q*4 + cls
    if (threadIdx.x < 4)
        atomicAdd(&acc[b * 16 + threadIdx.x * 4 + cls], s[threadIdx.x]);
}

// ===========================================================================
// K2: finalize scalar loss
// ===========================================================================
__global__ void lah_finalize(const float* __restrict__ acc, float* __restrict__ out) {
    float loss = 0.f;
#pragma unroll
    for (int b = 0; b < 2; ++b) {
#pragma unroll
        for (int c = 1; c < 4; ++c) {
            const float fp = acc[b * 16 + 0 + c];
            const float fn = acc[b * 16 + 4 + c];
            const float sxv = acc[b * 16 + 8 + c];
            const float syv = acc[b * 16 + 12 + c];
            loss += fmaxf(fp / (sxv + EPSV), fn / (syv + EPSV));
        }
    }
    out[0] = loss / 6.f;
}

extern "C" void kernel_launch(void* const* d_in, const int* in_sizes, int n_in,
                              void* d_out, int out_size, void* d_ws, size_t ws_size,
                              hipStream_t stream) {
    const float* x = (const float*)d_in[0];
    const int* y32 = (const int*)d_in[1];
    float* out = (float*)d_out;
    float* acc = (float*)d_ws;  // 32 floats

    hipMemsetAsync(d_ws, 0, 32 * sizeof(float), stream);
    mask_build<<<K0_NBLK, 256, 0, stream>>>(y32);
    lah_main<<<NBLK, 256, 0, stream>>>(x, acc);
    lah_finalize<<<1, 1, 0, stream>>>(acc, out);
}

// Round 6
// 65.075 us; speedup vs baseline: 1.2617x; 1.1034x over previous
//
#include <hip/hip_runtime.h>

// x[2][4][128][128][128] f32, y[2][1][128][128][128] int32
constexpr int SPB = 1 << 21;
constexpr float EPSV = 1e-6f;

// Static scratch: packed per-voxel mask, 4 MB.
// mask[v] = (center_class << 4) | OR_{3x3x3 clipped}(1 << y[v+d])
__device__ unsigned char g_mask[2 * SPB];

// ===========================================================================
// K0: build packed 27-neighborhood presence mask + center class (proven R5)
// ===========================================================================
constexpr int K0_ZSEG = 4;
constexpr int K0_NBLK = (2 * (128 / K0_ZSEG) * 128) / 4;  // 2048

struct MEnt { int pk, cx, cy; };

__device__ __forceinline__ MEnt k0_load(const int* __restrict__ yb, int s,
                                        int rbase0, bool ym1, bool yp1) {
    MEnt e;
    const int rb = (s << 14) | rbase0;
    int2 vc = *(const int2*)(yb + rb);
    int nib0 = 1 << vc.x, nib1 = 1 << vc.y;
    if (ym1) { int2 vm = *(const int2*)(yb + rb - 128); nib0 |= 1 << vm.x; nib1 |= 1 << vm.y; }
    if (yp1) { int2 vp = *(const int2*)(yb + rb + 128); nib0 |= 1 << vp.x; nib1 |= 1 << vp.y; }
    e.pk = nib0 | (nib1 << 8);
    e.cx = vc.x; e.cy = vc.y;
    return e;
}

__global__ __launch_bounds__(256) void mask_build(const int* __restrict__ y32) {
    const int wid = (blockIdx.x << 2) | (threadIdx.x >> 6);
    const int lane = threadIdx.x & 63;
    const int yy = wid & 127;
    const int zs = (wid >> 7) & 31;
    const int b = (wid >> 12) & 1;
    const int x0 = lane << 1;
    const int z0 = zs * K0_ZSEG;
    const bool ym1 = yy > 0, yp1 = yy < 127;
    const int rbase0 = (yy << 7) | x0;

    const int* __restrict__ yb = y32 + ((long)b << 21);
    unsigned char* __restrict__ mb = g_mask + ((long)b << 21);

    MEnt e0, e1;
    if (z0 > 0) e0 = k0_load(yb, z0 - 1, rbase0, ym1, yp1);
    else { e0.pk = 0; e0.cx = 0; e0.cy = 0; }
    e1 = k0_load(yb, z0, rbase0, ym1, yp1);

#pragma unroll
    for (int dz = 0; dz < K0_ZSEG; ++dz) {
        const int z = z0 + dz;
        MEnt e2;
        if (z + 1 < 128) e2 = k0_load(yb, z + 1, rbase0, ym1, yp1);
        else { e2.pk = 0; e2.cx = 0; e2.cy = 0; }

        const int zor = e0.pk | e1.pk | e2.pk;
        int orL = __shfl_up(zor, 1);
        if (lane == 0) orL = 0;
        int orR = __shfl_down(zor, 1);
        if (lane == 63) orR = 0;
        const int full0 = (zor | (zor >> 8) | (orL >> 8)) & 15;
        const int full1 = (zor | (zor >> 8) | orR) & 15;

        const unsigned short st =
            (unsigned short)((full0 | (e1.cx << 4)) | ((full1 | (e1.cy << 4)) << 8));
        *(unsigned short*)(mb + ((z << 14) | rbase0)) = st;

        e0 = e1; e1 = e2;
    }
}

// ===========================================================================
// K1: main pass. blockIdx%8 -> (b,cls) plane (XCD-local). Wave = row-pair,
// float4/lane, ring-of-3 y-product slices, 1-ahead prefetch.
// ===========================================================================
constexpr int ZSEG = 16;
constexpr int NZSEG = 128 / ZSEG;        // 8
constexpr int NBLK = 8 * NZSEG * 16;     // planes * zsegs * row-quads = 1024

struct S4 { float yp[4]; float cx[4]; };

__device__ __forceinline__ S4 conv_slice(float4 A4, float4 B4, bool elo, bool ehi) {
    float A[4] = {A4.x, A4.y, A4.z, A4.w};
    float B[4] = {B4.x, B4.y, B4.z, B4.w};
    S4 r;
    const bool lo = (threadIdx.x & 63) < 32;
#pragma unroll
    for (int e = 0; e < 4; ++e) {
        const float As = __shfl_xor(A[e], 32);
        const float Bs = __shfl_xor(B[e], 32);
        const float mid = lo ? As : Bs;                  // center row raw x
        const float oa = (elo && lo) ? 1.f : (1.f - A[e]);
        const float ob = (ehi && !lo) ? 1.f : (1.f - B[e]);
        r.yp[e] = (oa * (1.f - mid)) * ob;
        r.cx[e] = mid;
    }
    return r;
}

__global__ __launch_bounds__(256) void lah_main(const float* __restrict__ x,
                                                float* __restrict__ acc) {
    const int bid = blockIdx.x;
    const int plane = bid & 7;            // -> XCD (round-robin dispatch)
    const int b = plane >> 2, cls = plane & 3;
    const int inner = bid >> 3;           // 0..127
    const int zs = inner & (NZSEG - 1);   // 0..7
    const int rq = inner >> 3;            // 0..15
    const int wid4 = threadIdx.x >> 6;
    const int rp = rq * 4 + wid4;         // row-pair 0..63
    const int lane = threadIdx.x & 63;
    const int lx = lane & 31;
    const int hi = lane >> 5;
    const int z0 = zs * ZSEG;
    const int r = rp << 1;

    const int rowA = max(r - 1 + hi, 0);       // rows r-1 / r
    const int rowB = min(r + 1 + hi, 127);     // rows r+1 / r+2
    const int offA = (rowA << 7) | (lx << 2);
    const int offB = (rowB << 7) | (lx << 2);
    const int offC = ((r + hi) << 7) | (lx << 2);
    const bool elo = (rp == 0);
    const bool ehi = (rp == 63);

    const float* __restrict__ xp = x + ((long)plane << 21);
    const unsigned char* __restrict__ mb = g_mask + ((long)b << 21);

    float fp = 0.f, fn = 0.f, sx = 0.f, sy = 0.f;
    const float4 Z4 = make_float4(0.f, 0.f, 0.f, 0.f);

    S4 r0, r1, r2;
    if (z0 > 0) {
        float4 A = *(const float4*)(xp + ((z0 - 1) << 14) + offA);
        float4 B = *(const float4*)(xp + ((z0 - 1) << 14) + offB);
        r0 = conv_slice(A, B, elo, ehi);
    } else {
        r0 = conv_slice(Z4, Z4, elo, ehi);
    }
    {
        float4 A = *(const float4*)(xp + (z0 << 14) + offA);
        float4 B = *(const float4*)(xp + (z0 << 14) + offB);
        r1 = conv_slice(A, B, elo, ehi);
        A = *(const float4*)(xp + ((z0 + 1) << 14) + offA);
        B = *(const float4*)(xp + ((z0 + 1) << 14) + offB);
        r2 = conv_slice(A, B, elo, ehi);
    }
    unsigned mcur = *(const unsigned*)(mb + (z0 << 14) + offC);

#pragma unroll
    for (int dz = 0; dz < ZSEG; ++dz) {
        const int z = z0 + dz;
        // --- prefetch slice z+2 and mask z+1 (issued before compute) ---
        float4 A2 = Z4, B2 = Z4;
        if ((z + 2 < 128) && (dz < ZSEG - 1)) {
            A2 = *(const float4*)(xp + ((z + 2) << 14) + offA);
            B2 = *(const float4*)(xp + ((z + 2) << 14) + offB);
        }
        unsigned mnext = 0;
        if (dz < ZSEG - 1)
            mnext = *(const unsigned*)(mb + ((z + 1) << 14) + offC);

        // --- compute slice z from ring ---
        float zp[4];
#pragma unroll
        for (int e = 0; e < 4; ++e) zp[e] = r0.yp[e] * r1.yp[e] * r2.yp[e];
        float zl = __shfl_up(zp[3], 1);
        if (lx == 0) zl = 1.f;
        float zr = __shfl_down(zp[0], 1);
        if (lx == 31) zr = 1.f;
        const float t01 = zp[0] * zp[1], t12 = zp[1] * zp[2], t23 = zp[2] * zp[3];
        float Pv[4];
        Pv[0] = zl * t01; Pv[1] = t01 * zp[2]; Pv[2] = t12 * zp[3]; Pv[3] = t23 * zr;

#pragma unroll
        for (int e = 0; e < 4; ++e) {
            const int m = (mcur >> (e * 8)) & 0xFF;
            const bool pres = (m >> cls) & 1;
            const bool eq = (m >> 4) == cls;
            const float xv = r1.cx[e];
            sx += xv;
            fp += eq ? 0.f : xv * (pres ? 1.f : 2.f);
            fn += eq ? (1.f - xv) * (1.f + Pv[e]) : 0.f;
            sy += eq ? 1.f : 0.f;
        }

        // --- rotate ring (convert prefetched slice) ---
        r0 = r1; r1 = r2;
        r2 = conv_slice(A2, B2, elo, ehi);
        mcur = mnext;
    }

    // ---- reduce 4 scalars: wave shuffle -> block LDS -> global atomics ----
    float rr[4] = {fp, fn, sx, sy};
    __shared__ float s[4];
#pragma unroll
    for (int i = 0; i < 4; ++i) {
        float vv = rr[i];
#pragma unroll
        for (int off = 32; off >= 1; off >>= 1) vv += __shfl_down(vv, off);
        rr[i] = vv;
    }
    if (threadIdx.x < 4) s[threadIdx.x] = 0.f;
    __syncthreads();
    if (lane == 0) {
#pragma unroll
        for (int i = 0; i < 4; ++i) atomicAdd(&s[i], rr[i]);
    }
    __syncthreads();
    if (threadIdx.x < 4)
        atomicAdd(&acc[b * 16 + threadIdx.x * 4 + cls], s[threadIdx.x]);
}

// ===========================================================================
// K2: finalize scalar loss
// ===========================================================================
__global__ void lah_finalize(const float* __restrict__ acc, float* __restrict__ out) {
    float loss = 0.f;
#pragma unroll
    for (int b = 0; b < 2; ++b) {
#pragma unroll
        for (int c = 1; c < 4; ++c) {
            const float fp = acc[b * 16 + 0 + c];
            const float fn = acc[b * 16 + 4 + c];
            const float sxv = acc[b * 16 + 8 + c];
            const float syv = acc[b * 16 + 12 + c];
            loss += fmaxf(fp / (sxv + EPSV), fn / (syv + EPSV));
        }
    }
    out[0] = loss / 6.f;
}

extern "C" void kernel_launch(void* const* d_in, const int* in_sizes, int n_in,
                              void* d_out, int out_size, void* d_ws, size_t ws_size,
                              hipStream_t stream) {
    const float* x = (const float*)d_in[0];
    const int* y32 = (const int*)d_in[1];
    float* out = (float*)d_out;
    float* acc = (float*)d_ws;  // 32 floats

    hipMemsetAsync(d_ws, 0, 32 * sizeof(float), stream);
    mask_build<<<K0_NBLK, 256, 0, stream>>>(y32);
    lah_main<<<NBLK, 256, 0, stream>>>(x, acc);
    lah_finalize<<<1, 1, 0, stream>>>(acc, out);
}